// Round 1
// 513.988 us; speedup vs baseline: 1.3609x; 1.3609x over previous
//
#include <hip/hip_runtime.h>
#include <hip/hip_bf16.h>
#include <stdint.h>

// Problem constants (AdaLoRALinear): out = x @ (W + 2*(P*Lambda*mask)@Q)^T
#define M_TOK 8192   // batch tokens
#define NF    4096   // OUT_F
#define KF    4096   // IN_F
#define RANK  64

typedef __attribute__((ext_vector_type(8))) short short8;   // 8 x bf16 (4 VGPRs)
typedef __attribute__((ext_vector_type(4))) float floatx4;  // MFMA acc

typedef const uint32_t __attribute__((address_space(1)))* gp1_t;
typedef uint32_t __attribute__((address_space(3)))* lp3_t;

__device__ __forceinline__ void load_lds16(const void* g, void* l) {
  // async global->LDS, 16 B per lane; LDS dest must be uniform_base + lane*16
  __builtin_amdgcn_global_load_lds((gp1_t)g, (lp3_t)l, 16, 0, 0);
}

// ---------------- Kernel 1: x (fp32) -> bf16, 8 elems/thread ----------------
__global__ void cast_f32_bf16(const float* __restrict__ in,
                              __hip_bfloat16* __restrict__ out) {
  size_t i = ((size_t)blockIdx.x * blockDim.x + threadIdx.x) * 8;
  float4 a = *(const float4*)(in + i);
  float4 b = *(const float4*)(in + i + 4);
  union { __hip_bfloat16 h[8]; uint4 u; } pk;
  pk.h[0] = __float2bfloat16(a.x);
  pk.h[1] = __float2bfloat16(a.y);
  pk.h[2] = __float2bfloat16(a.z);
  pk.h[3] = __float2bfloat16(a.w);
  pk.h[4] = __float2bfloat16(b.x);
  pk.h[5] = __float2bfloat16(b.y);
  pk.h[6] = __float2bfloat16(b.z);
  pk.h[7] = __float2bfloat16(b.w);
  *(uint4*)(out + i) = pk.u;
}

// ---- Kernel 2: W_eff[n][k] = W[n][k] + 2*sum_r P[n][r]*Lam[r]*mask[r]*Q[r][k],
//      cast to bf16. Tile 64n x 64k per block, 256 threads, rank staged in LDS.
__global__ __launch_bounds__(256) void build_weff(
    const float* __restrict__ W, const float* __restrict__ P,
    const float* __restrict__ Lam, const float* __restrict__ Q,
    const unsigned char* __restrict__ mask,   // jnp.bool_ -> 1 byte/elem
    __hip_bfloat16* __restrict__ Wb) {
  __shared__ float lam[RANK];
  __shared__ float plT[RANK][68];  // [r][n_local], padded vs bank conflicts
  __shared__ float Qs[RANK][68];   // [r][k_local]

  const int t = threadIdx.x;
  const int n0 = blockIdx.y * 64;
  const int k0 = blockIdx.x * 64;

  if (t < RANK) lam[t] = 2.0f * Lam[t] * (mask[t] ? 1.0f : 0.0f);
  __syncthreads();

  {
    // stage P^T * lam : thread t covers n_local = t&63, r-range (t>>6)*16..+15
    const int nl = t & 63;
    const int rg = (t >> 6) * 16;
    const float* p = P + (size_t)(n0 + nl) * RANK + rg;
#pragma unroll
    for (int j = 0; j < 16; j += 4) {
      float4 v = *(const float4*)(p + j);
      plT[rg + j + 0][nl] = v.x * lam[rg + j + 0];
      plT[rg + j + 1][nl] = v.y * lam[rg + j + 1];
      plT[rg + j + 2][nl] = v.z * lam[rg + j + 2];
      plT[rg + j + 3][nl] = v.w * lam[rg + j + 3];
    }
    // stage Q tile: thread t covers r = t>>2, k-range (t&3)*16..+15
    const int r = t >> 2;
    const int kc = (t & 3) * 16;
    const float* q = Q + (size_t)r * KF + k0 + kc;
#pragma unroll
    for (int j = 0; j < 16; j += 4) {
      float4 v = *(const float4*)(q + j);
      Qs[r][kc + j + 0] = v.x;
      Qs[r][kc + j + 1] = v.y;
      Qs[r][kc + j + 2] = v.z;
      Qs[r][kc + j + 3] = v.w;
    }
  }
  __syncthreads();

  const int tn4 = t >> 4;  // 0..15 -> n-group of 4
  const int tk4 = t & 15;  // 0..15 -> k-group of 4
  float accv[4][4];
#pragma unroll
  for (int i = 0; i < 4; i++) {
    float4 w = *(const float4*)(W + (size_t)(n0 + tn4 * 4 + i) * KF + k0 + tk4 * 4);
    accv[i][0] = w.x; accv[i][1] = w.y; accv[i][2] = w.z; accv[i][3] = w.w;
  }
#pragma unroll 8
  for (int r = 0; r < RANK; r++) {
    float4 p4 = *(const float4*)&plT[r][tn4 * 4];
    float4 q4 = *(const float4*)&Qs[r][tk4 * 4];
#define ROWFMA(i, pi)                                                  \
    accv[i][0] += (pi) * q4.x; accv[i][1] += (pi) * q4.y;              \
    accv[i][2] += (pi) * q4.z; accv[i][3] += (pi) * q4.w;
    ROWFMA(0, p4.x) ROWFMA(1, p4.y) ROWFMA(2, p4.z) ROWFMA(3, p4.w)
#undef ROWFMA
  }
#pragma unroll
  for (int i = 0; i < 4; i++) {
    union { __hip_bfloat16 h[4]; uint2 u; } pk;
    pk.h[0] = __float2bfloat16(accv[i][0]);
    pk.h[1] = __float2bfloat16(accv[i][1]);
    pk.h[2] = __float2bfloat16(accv[i][2]);
    pk.h[3] = __float2bfloat16(accv[i][3]);
    *(uint2*)(Wb + (size_t)(n0 + tn4 * 4 + i) * KF + k0 + tk4 * 4) = pk.u;
  }
}

// ---- Kernel 3: C[m][n] = sum_k A[m][k]*B[n][k]; A,B bf16 row-major, C fp32.
//
// 256x256 tile, BK=64, 512 threads (8 waves, 2Mx4N), per-wave 128x64 output.
// Deep pipeline (m201-style): 4 phases per K-tile, raw s_barrier + counted
// s_waitcnt vmcnt(4) ONCE per K-tile (never 0 in the loop), setprio(1) around
// each 16-MFMA cluster, global_load_lds width-16 staging.
//
// LDS (128 KiB): A slots [0,32K)+[32K,64K), B slots [64K,96K)+[96K,128K).
// Each 32 KiB slot = two BK=32 panels (ks=0,1), each panel 256 rows x 64 B,
// with the m97 chunk-rotation swizzle (measured conflict-free):
//   logical chunk c of row r lives at physical chunk (c+(r>>1))&3.
//   Writer thread t (LDS dst forced to base+t*16) fetches global chunk
//   c = ((t&3)-((t>>3)&3))&3 of within-panel row t>>2 (+h*128).
//   Reader lane (frow,kq) reads physical chunk (kq+(frow>>1))&3 of its row.
//
// Race-freedom of the stage windows (all overwrites >=1 barrier after last
// read of the region):
//   - B frags of tile t are register-resident after phase0's lgkmcnt(0);
//     B(t+2) overwrites the same slot only in phases 2-3 (after phase-1's
//     end barrier).
//   - A slot cur^1 (tile t-1) was fully read last iteration; A(t+1) stages
//     into it in phases 0-1.
//   - vmcnt(4)+barrier at phase 3 guarantees A(t+1),B(t+1) have LANDED
//     before iteration t+1 reads them, while B(t+2)'s 4 loads stay in
//     flight across the barrier. Steady state: 4-12 loads outstanding.
// Last two iterations stage wrap-around tiles (kt+1)&63 / (kt+2)&63 into the
// schedule's normal safe slots: keeps control flow branch-free and vmcnt
// uniform; the redundant data is never read.
#define BM 256
#define BN 256
#define BK 64
#define NT (KF / BK)   // 64
#define ASL 16384      // elements per K-tile slot (256*64)

__device__ __forceinline__ void read_a4(short8 (&afr)[2][2],
                                        const __hip_bfloat16* Asl,
                                        int row_base, int swz) {
#pragma unroll
  for (int mm = 0; mm < 2; ++mm)
#pragma unroll
    for (int ks = 0; ks < 2; ++ks)
      afr[mm][ks] = *(const short8*)(Asl + ks * 8192 + (row_base + mm * 16) * 32 + swz);
}

template <int P>
__device__ __forceinline__ void mfma16(floatx4 (&acc)[8][4],
                                       const short8 (&afr)[2][2],
                                       const short8 (&bfr)[4][2]) {
#pragma unroll
  for (int ks = 0; ks < 2; ++ks)
#pragma unroll
    for (int mm = 0; mm < 2; ++mm)
#pragma unroll
      for (int nf = 0; nf < 4; ++nf)
        acc[P * 2 + mm][nf] = __builtin_amdgcn_mfma_f32_16x16x32_bf16(
            afr[mm][ks], bfr[nf][ks], acc[P * 2 + mm][nf], 0, 0, 0);
}

__global__ __launch_bounds__(512, 2) void gemm_xwt(
    const __hip_bfloat16* __restrict__ A,   // [M_TOK][KF]
    const __hip_bfloat16* __restrict__ B,   // [NF][KF]  (= W_eff, row = n)
    float* __restrict__ C) {                // [M_TOK][NF]
  extern __shared__ __hip_bfloat16 lds[];
  __hip_bfloat16* As = lds;            // 2 slots x 16384 elems
  __hip_bfloat16* Bs = lds + 2 * ASL;  // 2 slots x 16384 elems

  const int t = threadIdx.x;       // 0..511
  const int lane = t & 63;
  const int wave = t >> 6;         // 0..7
  const int wm = wave >> 2;        // 0..1 : M half (128 rows)
  const int wn = wave & 3;         // 0..3 : N quarter (64 cols)
  const int frow = lane & 15;
  const int kq = lane >> 4;
  const int swz = ((kq + (frow >> 1)) & 3) * 8;   // swizzled k-elem offset

  // XCD-bijective block swizzle: 512 wgs, 8 XCDs, 64 contiguous work/XCD.
  const int bid = blockIdx.x;
  const int wk = (bid & 7) * 64 + (bid >> 3);
  const int bm = wk >> 4;   // 0..31
  const int bn = wk & 15;   // 0..15

  // staging: thread t covers within-panel row (t>>2)(+h*128), global chunk c
  const int c = ((t & 3) - ((t >> 3) & 3)) & 3;
  const __hip_bfloat16* a_src = A + (size_t)(bm * BM + (t >> 2)) * KF + c * 8;
  const __hip_bfloat16* b_src = B + (size_t)(bn * BN + (t >> 2)) * KF + c * 8;
  __hip_bfloat16* a_dst = As + t * 8;
  __hip_bfloat16* b_dst = Bs + t * 8;

#define STAGE_A(kt_, slot_, h_)                                                        \
  do {                                                                                 \
    const __hip_bfloat16* s_ = a_src + ((kt_) & (NT - 1)) * BK + (size_t)(h_) * 128 * KF; \
    __hip_bfloat16* d_ = a_dst + (slot_) * ASL + (h_) * 4096;                          \
    load_lds16(s_, d_);                /* ks=0 panel */                                \
    load_lds16(s_ + 32, d_ + 8192);    /* ks=1 panel */                                \
  } while (0)
#define STAGE_B(kt_, slot_, h_)                                                        \
  do {                                                                                 \
    const __hip_bfloat16* s_ = b_src + ((kt_) & (NT - 1)) * BK + (size_t)(h_) * 128 * KF; \
    __hip_bfloat16* d_ = b_dst + (slot_) * ASL + (h_) * 4096;                          \
    load_lds16(s_, d_);                                                                \
    load_lds16(s_ + 32, d_ + 8192);                                                    \
  } while (0)

  floatx4 acc[8][4] = {};

  // prologue: A(0),B(0) (must land), B(1) (may fly). A(1) staged in iter 0.
  STAGE_A(0, 0, 0); STAGE_A(0, 0, 1);
  STAGE_B(0, 0, 0); STAGE_B(0, 0, 1);
  STAGE_B(1, 1, 0); STAGE_B(1, 1, 1);
  asm volatile("s_waitcnt vmcnt(4)" ::: "memory");   // A(0),B(0) landed
  __builtin_amdgcn_s_barrier();

  const int arow = wm * 128 + frow;
  const int brow = wn * 64 + frow;

  for (int kt = 0; kt < NT; ++kt) {
    const int cur = kt & 1;
    const __hip_bfloat16* Asl = As + cur * ASL;
    const __hip_bfloat16* Bsl = Bs + cur * ASL;

    short8 bfr[4][2];
    short8 afr[2][2];

    // ---------------- phase 0: all B (8 reads) + A q0 (4) ----------------
#pragma unroll
    for (int nf = 0; nf < 4; ++nf)
#pragma unroll
      for (int ks = 0; ks < 2; ++ks)
        bfr[nf][ks] = *(const short8*)(Bsl + ks * 8192 + (brow + nf * 16) * 32 + swz);
    read_a4(afr, Asl, arow + 0 * 32, swz);
    STAGE_A(kt + 1, cur ^ 1, 0);
    __builtin_amdgcn_sched_barrier(0);
    __builtin_amdgcn_s_barrier();
    asm volatile("s_waitcnt lgkmcnt(0)" ::: "memory");
    __builtin_amdgcn_sched_barrier(0);
    __builtin_amdgcn_s_setprio(1);
    mfma16<0>(acc, afr, bfr);
    __builtin_amdgcn_s_setprio(0);
    __builtin_amdgcn_sched_barrier(0);
    __builtin_amdgcn_s_barrier();

    // ---------------- phase 1: A q1 ----------------
    read_a4(afr, Asl, arow + 1 * 32, swz);
    STAGE_A(kt + 1, cur ^ 1, 1);
    __builtin_amdgcn_sched_barrier(0);
    __builtin_amdgcn_s_barrier();
    asm volatile("s_waitcnt lgkmcnt(0)" ::: "memory");
    __builtin_amdgcn_sched_barrier(0);
    __builtin_amdgcn_s_setprio(1);
    mfma16<1>(acc, afr, bfr);
    __builtin_amdgcn_s_setprio(0);
    __builtin_amdgcn_sched_barrier(0);
    __builtin_amdgcn_s_barrier();

    // ---------------- phase 2: A q2; B(t+2) half0 into cur slot ----------------
    read_a4(afr, Asl, arow + 2 * 32, swz);
    STAGE_B(kt + 2, cur, 0);
    __builtin_amdgcn_sched_barrier(0);
    __builtin_amdgcn_s_barrier();
    asm volatile("s_waitcnt lgkmcnt(0)" ::: "memory");
    __builtin_amdgcn_sched_barrier(0);
    __builtin_amdgcn_s_setprio(1);
    mfma16<2>(acc, afr, bfr);
    __builtin_amdgcn_s_setprio(0);
    __builtin_amdgcn_sched_barrier(0);
    __builtin_amdgcn_s_barrier();

    // ---------------- phase 3: A q3; B(t+2) half1; counted vmcnt ----------------
    read_a4(afr, Asl, arow + 3 * 32, swz);
    STAGE_B(kt + 2, cur, 1);
    __builtin_amdgcn_sched_barrier(0);
    __builtin_amdgcn_s_barrier();
    asm volatile("s_waitcnt lgkmcnt(0)" ::: "memory");
    __builtin_amdgcn_sched_barrier(0);
    __builtin_amdgcn_s_setprio(1);
    mfma16<3>(acc, afr, bfr);
    __builtin_amdgcn_s_setprio(0);
    __builtin_amdgcn_sched_barrier(0);
    // retire A(kt+1),B(kt+1); keep B(kt+2)'s 4 loads in flight
    asm volatile("s_waitcnt vmcnt(4)" ::: "memory");
    __builtin_amdgcn_s_barrier();
  }

#undef STAGE_A
#undef STAGE_B

  // epilogue: D mapping col(n)=lane&15, row(m)=(lane>>4)*4+reg  [m89-verified]
  const int col0 = bn * BN + wn * 64 + (lane & 15);
  const int row0 = bm * BM + wm * 128 + (lane >> 4) * 4;
#pragma unroll
  for (int mf = 0; mf < 8; ++mf)
#pragma unroll
    for (int nf = 0; nf < 4; ++nf)
#pragma unroll
      for (int r = 0; r < 4; ++r)
        C[(size_t)(row0 + mf * 16 + r) * NF + (col0 + nf * 16)] = acc[mf][nf][r];
}

extern "C" void kernel_launch(void* const* d_in, const int* in_sizes, int n_in,
                              void* d_out, int out_size, void* d_ws, size_t ws_size,
                              hipStream_t stream) {
  const float* x      = (const float*)d_in[0];  // [8192][4096]
  const float* weight = (const float*)d_in[1];  // [4096][4096]
  const float* P      = (const float*)d_in[2];  // [4096][64]
  const float* Lam    = (const float*)d_in[3];  // [64]
  const float* Q      = (const float*)d_in[4];  // [64][4096]
  const unsigned char* mask = (const unsigned char*)d_in[5];  // [64] bool8
  float* out = (float*)d_out;

  __hip_bfloat16* Xb = (__hip_bfloat16*)d_ws;                         // 64 MB
  __hip_bfloat16* Wb = (__hip_bfloat16*)((char*)d_ws + (size_t)M_TOK * KF * 2);  // 32 MB

  static int smem_set = 0;
  if (!smem_set) {
    hipFuncSetAttribute((const void*)gemm_xwt,
                        hipFuncAttributeMaxDynamicSharedMemorySize, 131072);
    smem_set = 1;
  }

  // 1) x -> bf16
  cast_f32_bf16<<<(M_TOK * KF) / (256 * 8), 256, 0, stream>>>(x, Xb);
  // 2) W_eff -> bf16
  build_weff<<<dim3(KF / 64, NF / 64), 256, 0, stream>>>(weight, P, Lam, Q, mask, Wb);
  // 3) out = Xb @ Wb^T   (512 blocks = 32 bm x 16 bn, XCD-swizzled)
  gemm_xwt<<<dim3((M_TOK / BM) * (NF / BN)), 512, 131072, stream>>>(Xb, Wb, out);
}